// Round 11
// baseline (224.692 us; speedup 1.0000x reference)
//
#include <hip/hip_runtime.h>

#define BB 8
#define CC 96
#define HH 224
#define WW 224

typedef _Float16 h2 __attribute__((ext_vector_type(2)));
__device__ __forceinline__ h2 u2h(unsigned u) { return __builtin_bit_cast(h2, u); }
__device__ __forceinline__ unsigned pkrtz(float a, float b) {
    return __builtin_bit_cast(unsigned, __builtin_amdgcn_cvt_pkrtz(a, b));
}

#if __has_builtin(__builtin_amdgcn_fdot2)
#define FDOT2(a, b, c) __builtin_amdgcn_fdot2((a), (b), (c), false)
#else
#define FDOT2(a, b, c) ((float)(a).x * (float)(b).x + (float)(a).y * (float)(b).y + (c))
#endif

// ---------------------------------------------------------------------------
// levels_fused: ONE block per (b,c). Levels 1+2 entirely in LDS. (unchanged)
// ---------------------------------------------------------------------------
__global__ __launch_bounds__(512, 4) void levels_fused(
    const float* __restrict__ x,
    float* __restrict__ c1,        // (B*C,4,56,56)
    float* __restrict__ c2,        // (B*C,4,28,28)
    const float* __restrict__ wt1, const float* __restrict__ ws1,
    const float* __restrict__ wt2, const float* __restrict__ ws2)
{
    const int bc = blockIdx.x, c = bc % CC;
    const int t = threadIdx.x;

    __shared__ unsigned s_c1[112 * 58];
    __shared__ unsigned s_sb1[4 * 60 * 31];
    __shared__ unsigned s_cur2[56 * 30];
    __shared__ unsigned s_sb2[4 * 32 * 17];
    __shared__ unsigned s_w2[240];

    for (int i = t; i < 4 * 60 * 31; i += 512) s_sb1[i] = 0;
    for (int i = t; i < 4 * 32 * 17; i += 512) s_sb2[i] = 0;

    if (t < 80) {
        int knl = t / 10;
        int par = t & 1, row = (t % 10) >> 1;
        int lvl = knl >> 2, s = knl & 3;
        const float* wt  = lvl ? wt2 : wt1;
        const float* wsc = lvl ? ws2 : ws1;
        float sc = 0.5f * wsc[c * 4 + s];
        float wv[5];
        #pragma unroll
        for (int j = 0; j < 5; ++j) wv[j] = wt[(c * 4 + s) * 25 + row * 5 + j] * sc;
        unsigned* dst = &s_w2[(knl * 2 + par) * 15 + row * 3];
        if (par == 0) {
            dst[0] = pkrtz(wv[0], wv[1]);
            dst[1] = pkrtz(wv[2], wv[3]);
            dst[2] = pkrtz(wv[4], 0.f);
        } else {
            dst[0] = pkrtz(0.f, wv[0]);
            dst[1] = pkrtz(wv[1], wv[2]);
            dst[2] = pkrtz(wv[3], wv[4]);
        }
    }

    const float* xp = x + (size_t)bc * HH * WW;
    for (int idx = t; idx < 112 * 56; idx += 512) {
        int r = idx / 56, g = idx % 56;
        const float* r0 = xp + (size_t)(2 * r) * WW + 4 * g;
        const float* r1 = r0 + WW;
        float4 a = *(const float4*)r0;
        float4 b = *(const float4*)r1;
        s_c1[r * 58 + g] = pkrtz(0.5f * (a.x + a.y + b.x + b.y),
                                 0.5f * (a.z + a.w + b.z + b.w));
    }
    __syncthreads();

    for (int idx = t; idx < 56 * 28; idx += 512) {
        int sr = idx / 28, sc2 = idx % 28;
        uint2 tp = *(const uint2*)&s_c1[(2 * sr) * 58 + 2 * sc2];
        uint2 bt = *(const uint2*)&s_c1[(2 * sr + 1) * 58 + 2 * sc2];
        h2 t0 = u2h(tp.x), t1 = u2h(tp.y), b0 = u2h(bt.x), b1 = u2h(bt.y);
        float P0 = (float)t0.x + (float)t0.y, M0 = (float)t0.x - (float)t0.y;
        float R0 = (float)b0.x + (float)b0.y, Q0 = (float)b0.x - (float)b0.y;
        float P1 = (float)t1.x + (float)t1.y, M1 = (float)t1.x - (float)t1.y;
        float R1 = (float)b1.x + (float)b1.y, Q1 = (float)b1.x - (float)b1.y;
        int o = (sr + 2) * 31 + (sc2 + 1);
        s_sb1[0 * 1860 + o] = pkrtz(P0 + R0, P1 + R1);
        s_sb1[1 * 1860 + o] = pkrtz(M0 + Q0, M1 + Q1);
        s_sb1[2 * 1860 + o] = pkrtz(P0 - R0, P1 - R1);
        s_sb1[3 * 1860 + o] = pkrtz(M0 - Q0, M1 - Q1);
        s_cur2[sr * 30 + sc2] = pkrtz(0.5f * (P0 + R0), 0.5f * (P1 + R1));
    }
    __syncthreads();

    if (t < 28 * 14) {
        int sr = t / 14, sc2 = t % 14;
        uint2 tp = *(const uint2*)&s_cur2[(2 * sr) * 30 + 2 * sc2];
        uint2 bt = *(const uint2*)&s_cur2[(2 * sr + 1) * 30 + 2 * sc2];
        h2 t0 = u2h(tp.x), t1 = u2h(tp.y), b0 = u2h(bt.x), b1 = u2h(bt.y);
        float P0 = (float)t0.x + (float)t0.y, M0 = (float)t0.x - (float)t0.y;
        float R0 = (float)b0.x + (float)b0.y, Q0 = (float)b0.x - (float)b0.y;
        float P1 = (float)t1.x + (float)t1.y, M1 = (float)t1.x - (float)t1.y;
        float R1 = (float)b1.x + (float)b1.y, Q1 = (float)b1.x - (float)b1.y;
        int o = (sr + 2) * 17 + (sc2 + 1);
        s_sb2[0 * 544 + o] = pkrtz(P0 + R0, P1 + R1);
        s_sb2[1 * 544 + o] = pkrtz(M0 + Q0, M1 + Q1);
        s_sb2[2 * 544 + o] = pkrtz(P0 - R0, P1 - R1);
        s_sb2[3 * 544 + o] = pkrtz(M0 - Q0, M1 - Q1);
    }

    {
        const int s = t >> 7, lane = t & 127;
        const int q = lane & 63, half = lane >> 6;
        if (q < 56) {
            const int par = q & 1, d0 = q >> 1, ps = half * 28;
            h2 w[5][3];
            {
                const unsigned* wp = &s_w2[(s * 2 + par) * 15];
                #pragma unroll
                for (int ki = 0; ki < 5; ++ki)
                    #pragma unroll
                    for (int m = 0; m < 3; ++m) w[ki][m] = u2h(wp[ki * 3 + m]);
            }
            float acc[28];
            #pragma unroll
            for (int r = 0; r < 28; ++r) acc[r] = 0.f;
            #pragma unroll
            for (int ri = 0; ri < 32; ++ri) {
                const unsigned* rp = &s_sb1[s * 1860 + (ps + ri) * 31 + d0];
                h2 g0 = u2h(rp[0]), g1 = u2h(rp[1]), g2 = u2h(rp[2]);
                #pragma unroll
                for (int ki = 0; ki < 5; ++ki) {
                    int r = ri - ki;
                    if (r >= 0 && r < 28)
                        acc[r] = FDOT2(g0, w[ki][0],
                                 FDOT2(g1, w[ki][1],
                                 FDOT2(g2, w[ki][2], acc[r])));
                }
            }
            const size_t ob = ((size_t)(bc * 4 + s) * 56 + ps) * 56 + q;
            #pragma unroll
            for (int r = 0; r < 28; ++r)
                c1[ob + (size_t)r * 56] = acc[r];
        }
    }
    __syncthreads();

    if (t < 112) {
        const int s = t / 28, q = t % 28;
        const int par = q & 1, d0 = q >> 1;
        h2 w[5][3];
        {
            const unsigned* wp = &s_w2[((4 + s) * 2 + par) * 15];
            #pragma unroll
            for (int ki = 0; ki < 5; ++ki)
                #pragma unroll
                for (int m = 0; m < 3; ++m) w[ki][m] = u2h(wp[ki * 3 + m]);
        }
        float acc[28];
        #pragma unroll
        for (int r = 0; r < 28; ++r) acc[r] = 0.f;
        #pragma unroll
        for (int ri = 0; ri < 32; ++ri) {
            const unsigned* rp = &s_sb2[s * 544 + ri * 17 + d0];
            h2 g0 = u2h(rp[0]), g1 = u2h(rp[1]), g2 = u2h(rp[2]);
            #pragma unroll
            for (int ki = 0; ki < 5; ++ki) {
                int r = ri - ki;
                if (r >= 0 && r < 28)
                    acc[r] = FDOT2(g0, w[ki][0],
                             FDOT2(g1, w[ki][1],
                             FDOT2(g2, w[ki][2], acc[r])));
            }
        }
        const size_t ob = (size_t)(bc * 4 + s) * 28 * 28 + q;
        #pragma unroll
        for (int r = 0; r < 28; ++r)
            c2[ob + (size_t)r * 28] = acc[r];
    }
}

// ---------------------------------------------------------------------------
// final_fused_v7: 128 threads (2 waves), 32x32 output tile, grid 7x7x768.
// Exact lane mappings per phase:
//   stage      : 400 uint2 units (~3.1/thread)
//   base conv  : 32 cols x 4 row-quarters = 128 (8 outputs each)
//   subband    : 4 bands x 16 cols x 2 halves = 128 (8 outputs each)
//   ihaar1     : 64 c1 positions (wave 0)
//   combine    : 32 cols x 4 quarters = 128
// LDS ~9 KB; 2-wave barriers only. VGPR target <=85 (launch_bounds 128,6).
// ---------------------------------------------------------------------------
__global__ __launch_bounds__(128, 6) void final_fused_v7(
    const float* __restrict__ x,
    const float* __restrict__ bw,
    const float* __restrict__ bb,
    const float* __restrict__ bs,
    const float* __restrict__ wt0,
    const float* __restrict__ wsc0,
    const float* __restrict__ c1,   // (B*C,4,56,56)
    const float* __restrict__ c2,   // (B*C,4,28,28)
    float* __restrict__ out)
{
    const int bc = blockIdx.z, c = bc % CC;
    const int t = threadIdx.x;
    const int ox = 32 * blockIdx.x, oy = 32 * blockIdx.y;

    __shared__ unsigned s_x[40 * 22];      // fp16 x-tile (40x40), stride 22 dw
    __shared__ unsigned s_sb[4 * 20 * 11]; // fp16 L0 subbands (20x20), stride 11
    __shared__ float s_rec1[16 * 17];
    __shared__ float s_rec2[8 * 9];
    __shared__ unsigned s_w2[150];
    _Float16* const s_cvh = reinterpret_cast<_Float16*>(s_x);  // overlay

    // ---- weights: folded, parity-padded half2 triplets ----
    if (t < 50) {
        int par = t & 1, row = (t >> 1) % 5, knl = t / 10;
        float wv[5];
        if (knl == 0) {
            float sc = bs[c];
            #pragma unroll
            for (int j = 0; j < 5; ++j) wv[j] = bw[c * 25 + row * 5 + j] * sc;
        } else {
            int s = knl - 1;
            float sc = 0.5f * wsc0[c * 4 + s];
            #pragma unroll
            for (int j = 0; j < 5; ++j) wv[j] = wt0[(c * 4 + s) * 25 + row * 5 + j] * sc;
        }
        unsigned* dst = &s_w2[((knl * 2 + par) * 5 + row) * 3];
        if (par == 0) {
            dst[0] = pkrtz(wv[0], wv[1]);
            dst[1] = pkrtz(wv[2], wv[3]);
            dst[2] = pkrtz(wv[4], 0.f);
        } else {
            dst[0] = pkrtz(0.f, wv[0]);
            dst[1] = pkrtz(wv[1], wv[2]);
            dst[2] = pkrtz(wv[3], wv[4]);
        }
    }

    // ---- coeff loads issued early ----
    float c2v[4], c1v[4];
    if (t < 16) {
        const int p2 = t >> 2, q2 = t & 3;
        const size_t b2 = (((size_t)bc * 4) * 28 + 4 * blockIdx.y + p2) * 28
                        + 4 * blockIdx.x + q2;
        #pragma unroll
        for (int s = 0; s < 4; ++s) c2v[s] = c2[b2 + (size_t)s * 784];
    }
    const int p1 = (t & 63) >> 3, q1 = t & 7;
    if (t < 64) {
        const size_t b1 = (((size_t)bc * 4) * 56 + 8 * blockIdx.y + p1) * 56
                        + 8 * blockIdx.x + q1;
        #pragma unroll
        for (int s = 0; s < 4; ++s) c1v[s] = c1[b1 + (size_t)s * 3136];
    }

    // ---- phase 1: stage 40x40 x-tile as packed fp16 ----
    const float* xp = x + (size_t)bc * HH * WW;
    const int gy0 = oy - 4, gx0 = ox - 4;
    #pragma unroll
    for (int it = 0; it < 4; ++it) {
        int idx = t + it * 128;
        if (idx < 400) {
            int r = idx / 10, j = idx % 10;
            int gr = gy0 + r, gc = gx0 + 4 * j;
            float4 v = make_float4(0.f, 0.f, 0.f, 0.f);
            if (gr >= 0 && gr < HH && gc >= 0 && gc + 3 < WW)
                v = *(const float4*)(xp + (size_t)gr * WW + gc);
            uint2 pp;
            pp.x = pkrtz(v.x, v.y);
            pp.y = pkrtz(v.z, v.w);
            *(uint2*)&s_x[r * 22 + 2 * j] = pp;
        }
    }

    // ---- ihaar level 2: c2 -> s_rec2 (8x8) ----
    if (t < 16) {
        const int p2 = t >> 2, q2 = t & 3;
        float ll = c2v[0], lh = c2v[1], hl = c2v[2], hh = c2v[3];
        float a  = 0.5f * (ll + lh + hl + hh);
        float b  = 0.5f * (ll - lh + hl - hh);
        float cv = 0.5f * (ll + lh - hl - hh);
        float d  = 0.5f * (ll - lh - hl + hh);
        float* rp = &s_rec2[(2 * p2) * 9 + 2 * q2];
        rp[0] = a; rp[1] = b; rp[9] = cv; rp[10] = d;
    }
    __syncthreads();

    // ---- phase 2: butterfly + base conv + ihaar1 ----
    #pragma unroll
    for (int it = 0; it < 2; ++it) {
        int idx = t + it * 128;
        if (idx < 200) {
            int sr = idx / 10, g = idx % 10;
            uint2 tp = *(const uint2*)&s_x[(2 * sr) * 22 + 2 * g];
            uint2 bt = *(const uint2*)&s_x[(2 * sr + 1) * 22 + 2 * g];
            h2 t0 = u2h(tp.x), t1 = u2h(tp.y), b0 = u2h(bt.x), b1 = u2h(bt.y);
            float P0 = (float)t0.x + (float)t0.y, M0 = (float)t0.x - (float)t0.y;
            float R0 = (float)b0.x + (float)b0.y, Q0 = (float)b0.x - (float)b0.y;
            float P1 = (float)t1.x + (float)t1.y, M1 = (float)t1.x - (float)t1.y;
            float R1 = (float)b1.x + (float)b1.y, Q1 = (float)b1.x - (float)b1.y;
            int o = sr * 11 + g;
            s_sb[0 * 220 + o] = pkrtz(P0 + R0, P1 + R1);
            s_sb[1 * 220 + o] = pkrtz(M0 + Q0, M1 + Q1);
            s_sb[2 * 220 + o] = pkrtz(P0 - R0, P1 - R1);
            s_sb[3 * 220 + o] = pkrtz(M0 - Q0, M1 - Q1);
        }
    }

    // base conv: col q (0..31), quarter rq (0..3); 8 outputs each
    const int qb = t & 31, rq = t >> 5;
    float bacc[8];
    {
        const int par = qb & 1, d0 = (qb + 2) >> 1;
        h2 w[5][3];
        {
            const unsigned* wp = &s_w2[(par * 5) * 3];
            #pragma unroll
            for (int ki = 0; ki < 5; ++ki)
                #pragma unroll
                for (int m = 0; m < 3; ++m) w[ki][m] = u2h(wp[ki * 3 + m]);
        }
        #pragma unroll
        for (int r = 0; r < 8; ++r) bacc[r] = 0.f;
        #pragma unroll
        for (int ri = 0; ri < 12; ++ri) {
            const unsigned* rp = &s_x[(rq * 8 + ri + 2) * 22 + d0];
            h2 g0 = u2h(rp[0]), g1 = u2h(rp[1]), g2 = u2h(rp[2]);
            #pragma unroll
            for (int ki = 0; ki < 5; ++ki) {
                int r = ri - ki;
                if (r >= 0 && r < 8)
                    bacc[r] = FDOT2(g0, w[ki][0],
                              FDOT2(g1, w[ki][1],
                              FDOT2(g2, w[ki][2], bacc[r])));
            }
        }
    }

    // ihaar level 1: (c1 with LL += rec2) -> s_rec1 (16x16)
    if (t < 64) {
        float ll = c1v[0] + s_rec2[p1 * 9 + q1];
        float lh = c1v[1], hl = c1v[2], hh = c1v[3];
        float a  = 0.5f * (ll + lh + hl + hh);
        float b  = 0.5f * (ll - lh + hl - hh);
        float cv = 0.5f * (ll + lh - hl - hh);
        float d  = 0.5f * (ll - lh - hl + hh);
        float* rp = &s_rec1[(2 * p1) * 17 + 2 * q1];
        rp[0] = a; rp[1] = b; rp[17] = cv; rp[18] = d;
    }
    __syncthreads();

    // ---- phase 3: subband conv (band s, col q, half hf) -> s_cvh overlay ----
    {
        const int s = t >> 5, hf = (t >> 4) & 1, q = t & 15;
        const int par = q & 1, d0 = q >> 1;
        h2 w[5][3];
        {
            const unsigned* wp = &s_w2[(((1 + s) * 2 + par) * 5) * 3];
            #pragma unroll
            for (int ki = 0; ki < 5; ++ki)
                #pragma unroll
                for (int m = 0; m < 3; ++m) w[ki][m] = u2h(wp[ki * 3 + m]);
        }
        float acc[8];
        #pragma unroll
        for (int r = 0; r < 8; ++r) acc[r] = 0.f;
        #pragma unroll
        for (int ri = 0; ri < 12; ++ri) {
            const unsigned* rp = &s_sb[s * 220 + (hf * 8 + ri) * 11 + d0];
            h2 g0 = u2h(rp[0]), g1 = u2h(rp[1]), g2 = u2h(rp[2]);
            #pragma unroll
            for (int ki = 0; ki < 5; ++ki) {
                int r = ri - ki;
                if (r >= 0 && r < 8)
                    acc[r] = FDOT2(g0, w[ki][0],
                             FDOT2(g1, w[ki][1],
                             FDOT2(g2, w[ki][2], acc[r])));
            }
        }
        #pragma unroll
        for (int r = 0; r < 8; ++r)
            s_cvh[(s * 16 + hf * 8 + r) * 18 + q] = (_Float16)acc[r];
    }
    __syncthreads();

    // ---- phase 4: ihaar level 0 + base + store ----
    {
        const float bbv = bb[c];
        const int qs = qb >> 1;
        const float sx = (qb & 1) ? -1.f : 1.f;
        float* op = out + ((size_t)bc * HH + oy + rq * 8) * WW + ox + qb;
        #pragma unroll
        for (int j = 0; j < 4; ++j) {
            const int p = rq * 4 + j;
            float ll = (float)s_cvh[(0 * 16 + p) * 18 + qs] + s_rec1[p * 17 + qs];
            float lh = (float)s_cvh[(1 * 16 + p) * 18 + qs];
            float hl = (float)s_cvh[(2 * 16 + p) * 18 + qs];
            float hh = (float)s_cvh[(3 * 16 + p) * 18 + qs];
            float e0 = ll + sx * lh;
            float e1 = hl + sx * hh;
            float top = 0.5f * (e0 + e1);
            float bot = 0.5f * (e0 - e1);
            op[(size_t)(2 * j) * WW]     = bacc[2 * j]     + bbv + top;
            op[(size_t)(2 * j + 1) * WW] = bacc[2 * j + 1] + bbv + bot;
        }
    }
}

extern "C" void kernel_launch(void* const* d_in, const int* in_sizes, int n_in,
                              void* d_out, int out_size, void* d_ws, size_t ws_size,
                              hipStream_t stream) {
    const float* x          = (const float*)d_in[0];
    const float* base_w     = (const float*)d_in[1];
    const float* base_b     = (const float*)d_in[2];
    const float* base_scale = (const float*)d_in[3];
    const float* wconv_w    = (const float*)d_in[4]; // (3, 384, 25)
    const float* wscale     = (const float*)d_in[5]; // (3, 384)
    float* out = (float*)d_out;
    float* ws  = (float*)d_ws;

    const size_t n1 = (size_t)BB * CC * 4 * 56 * 56;   // coeffs1

    float* coeffs1 = ws;
    float* coeffs2 = coeffs1 + n1;

    const int z = BB * CC;

    // levels 1+2 fully fused, one block per (b,c)
    levels_fused<<<z, 512, 0, stream>>>(
        x, coeffs1, coeffs2,
        wconv_w + 1 * 384 * 25, wscale + 1 * 384,
        wconv_w + 2 * 384 * 25, wscale + 2 * 384);
    // final: 2-wave blocks, 32x32 tiles
    final_fused_v7<<<dim3(7, 7, z), 128, 0, stream>>>(
        x, base_w, base_b, base_scale,
        wconv_w + 0 * 384 * 25, wscale + 0 * 384, coeffs1, coeffs2, out);
}

// Round 12
// 150.489 us; speedup vs baseline: 1.4931x; 1.4931x over previous
//
#include <hip/hip_runtime.h>

#define BB 8
#define CC 96
#define HH 224
#define WW 224

typedef _Float16 h2 __attribute__((ext_vector_type(2)));
__device__ __forceinline__ h2 u2h(unsigned u) { return __builtin_bit_cast(h2, u); }
__device__ __forceinline__ unsigned pkrtz(float a, float b) {
    return __builtin_bit_cast(unsigned, __builtin_amdgcn_cvt_pkrtz(a, b));
}

#if __has_builtin(__builtin_amdgcn_fdot2)
#define FDOT2(a, b, c) __builtin_amdgcn_fdot2((a), (b), (c), false)
#else
#define FDOT2(a, b, c) ((float)(a).x * (float)(b).x + (float)(a).y * (float)(b).y + (c))
#endif

// ---------------------------------------------------------------------------
// levels_fused: ONE block per (b,c). Levels 1+2 entirely in LDS. (unchanged)
// ---------------------------------------------------------------------------
__global__ __launch_bounds__(512, 4) void levels_fused(
    const float* __restrict__ x,
    float* __restrict__ c1,        // (B*C,4,56,56)
    float* __restrict__ c2,        // (B*C,4,28,28)
    const float* __restrict__ wt1, const float* __restrict__ ws1,
    const float* __restrict__ wt2, const float* __restrict__ ws2)
{
    const int bc = blockIdx.x, c = bc % CC;
    const int t = threadIdx.x;

    __shared__ unsigned s_c1[112 * 58];
    __shared__ unsigned s_sb1[4 * 60 * 31];
    __shared__ unsigned s_cur2[56 * 30];
    __shared__ unsigned s_sb2[4 * 32 * 17];
    __shared__ unsigned s_w2[240];

    for (int i = t; i < 4 * 60 * 31; i += 512) s_sb1[i] = 0;
    for (int i = t; i < 4 * 32 * 17; i += 512) s_sb2[i] = 0;

    if (t < 80) {
        int knl = t / 10;
        int par = t & 1, row = (t % 10) >> 1;
        int lvl = knl >> 2, s = knl & 3;
        const float* wt  = lvl ? wt2 : wt1;
        const float* wsc = lvl ? ws2 : ws1;
        float sc = 0.5f * wsc[c * 4 + s];
        float wv[5];
        #pragma unroll
        for (int j = 0; j < 5; ++j) wv[j] = wt[(c * 4 + s) * 25 + row * 5 + j] * sc;
        unsigned* dst = &s_w2[(knl * 2 + par) * 15 + row * 3];
        if (par == 0) {
            dst[0] = pkrtz(wv[0], wv[1]);
            dst[1] = pkrtz(wv[2], wv[3]);
            dst[2] = pkrtz(wv[4], 0.f);
        } else {
            dst[0] = pkrtz(0.f, wv[0]);
            dst[1] = pkrtz(wv[1], wv[2]);
            dst[2] = pkrtz(wv[3], wv[4]);
        }
    }

    const float* xp = x + (size_t)bc * HH * WW;
    for (int idx = t; idx < 112 * 56; idx += 512) {
        int r = idx / 56, g = idx % 56;
        const float* r0 = xp + (size_t)(2 * r) * WW + 4 * g;
        const float* r1 = r0 + WW;
        float4 a = *(const float4*)r0;
        float4 b = *(const float4*)r1;
        s_c1[r * 58 + g] = pkrtz(0.5f * (a.x + a.y + b.x + b.y),
                                 0.5f * (a.z + a.w + b.z + b.w));
    }
    __syncthreads();

    for (int idx = t; idx < 56 * 28; idx += 512) {
        int sr = idx / 28, sc2 = idx % 28;
        uint2 tp = *(const uint2*)&s_c1[(2 * sr) * 58 + 2 * sc2];
        uint2 bt = *(const uint2*)&s_c1[(2 * sr + 1) * 58 + 2 * sc2];
        h2 t0 = u2h(tp.x), t1 = u2h(tp.y), b0 = u2h(bt.x), b1 = u2h(bt.y);
        float P0 = (float)t0.x + (float)t0.y, M0 = (float)t0.x - (float)t0.y;
        float R0 = (float)b0.x + (float)b0.y, Q0 = (float)b0.x - (float)b0.y;
        float P1 = (float)t1.x + (float)t1.y, M1 = (float)t1.x - (float)t1.y;
        float R1 = (float)b1.x + (float)b1.y, Q1 = (float)b1.x - (float)b1.y;
        int o = (sr + 2) * 31 + (sc2 + 1);
        s_sb1[0 * 1860 + o] = pkrtz(P0 + R0, P1 + R1);
        s_sb1[1 * 1860 + o] = pkrtz(M0 + Q0, M1 + Q1);
        s_sb1[2 * 1860 + o] = pkrtz(P0 - R0, P1 - R1);
        s_sb1[3 * 1860 + o] = pkrtz(M0 - Q0, M1 - Q1);
        s_cur2[sr * 30 + sc2] = pkrtz(0.5f * (P0 + R0), 0.5f * (P1 + R1));
    }
    __syncthreads();

    if (t < 28 * 14) {
        int sr = t / 14, sc2 = t % 14;
        uint2 tp = *(const uint2*)&s_cur2[(2 * sr) * 30 + 2 * sc2];
        uint2 bt = *(const uint2*)&s_cur2[(2 * sr + 1) * 30 + 2 * sc2];
        h2 t0 = u2h(tp.x), t1 = u2h(tp.y), b0 = u2h(bt.x), b1 = u2h(bt.y);
        float P0 = (float)t0.x + (float)t0.y, M0 = (float)t0.x - (float)t0.y;
        float R0 = (float)b0.x + (float)b0.y, Q0 = (float)b0.x - (float)b0.y;
        float P1 = (float)t1.x + (float)t1.y, M1 = (float)t1.x - (float)t1.y;
        float R1 = (float)b1.x + (float)b1.y, Q1 = (float)b1.x - (float)b1.y;
        int o = (sr + 2) * 17 + (sc2 + 1);
        s_sb2[0 * 544 + o] = pkrtz(P0 + R0, P1 + R1);
        s_sb2[1 * 544 + o] = pkrtz(M0 + Q0, M1 + Q1);
        s_sb2[2 * 544 + o] = pkrtz(P0 - R0, P1 - R1);
        s_sb2[3 * 544 + o] = pkrtz(M0 - Q0, M1 - Q1);
    }

    {
        const int s = t >> 7, lane = t & 127;
        const int q = lane & 63, half = lane >> 6;
        if (q < 56) {
            const int par = q & 1, d0 = q >> 1, ps = half * 28;
            h2 w[5][3];
            {
                const unsigned* wp = &s_w2[(s * 2 + par) * 15];
                #pragma unroll
                for (int ki = 0; ki < 5; ++ki)
                    #pragma unroll
                    for (int m = 0; m < 3; ++m) w[ki][m] = u2h(wp[ki * 3 + m]);
            }
            float acc[28];
            #pragma unroll
            for (int r = 0; r < 28; ++r) acc[r] = 0.f;
            #pragma unroll
            for (int ri = 0; ri < 32; ++ri) {
                const unsigned* rp = &s_sb1[s * 1860 + (ps + ri) * 31 + d0];
                h2 g0 = u2h(rp[0]), g1 = u2h(rp[1]), g2 = u2h(rp[2]);
                #pragma unroll
                for (int ki = 0; ki < 5; ++ki) {
                    int r = ri - ki;
                    if (r >= 0 && r < 28)
                        acc[r] = FDOT2(g0, w[ki][0],
                                 FDOT2(g1, w[ki][1],
                                 FDOT2(g2, w[ki][2], acc[r])));
                }
            }
            const size_t ob = ((size_t)(bc * 4 + s) * 56 + ps) * 56 + q;
            #pragma unroll
            for (int r = 0; r < 28; ++r)
                c1[ob + (size_t)r * 56] = acc[r];
        }
    }
    __syncthreads();

    if (t < 112) {
        const int s = t / 28, q = t % 28;
        const int par = q & 1, d0 = q >> 1;
        h2 w[5][3];
        {
            const unsigned* wp = &s_w2[((4 + s) * 2 + par) * 15];
            #pragma unroll
            for (int ki = 0; ki < 5; ++ki)
                #pragma unroll
                for (int m = 0; m < 3; ++m) w[ki][m] = u2h(wp[ki * 3 + m]);
        }
        float acc[28];
        #pragma unroll
        for (int r = 0; r < 28; ++r) acc[r] = 0.f;
        #pragma unroll
        for (int ri = 0; ri < 32; ++ri) {
            const unsigned* rp = &s_sb2[s * 544 + ri * 17 + d0];
            h2 g0 = u2h(rp[0]), g1 = u2h(rp[1]), g2 = u2h(rp[2]);
            #pragma unroll
            for (int ki = 0; ki < 5; ++ki) {
                int r = ri - ki;
                if (r >= 0 && r < 28)
                    acc[r] = FDOT2(g0, w[ki][0],
                             FDOT2(g1, w[ki][1],
                             FDOT2(g2, w[ki][2], acc[r])));
            }
        }
        const size_t ob = (size_t)(bc * 4 + s) * 28 * 28 + q;
        #pragma unroll
        for (int r = 0; r < 28; ++r)
            c2[ob + (size_t)r * 28] = acc[r];
    }
}

// ---------------------------------------------------------------------------
// final_fused_v8: v5 structure (256 thr, 56x56 tile, grid 4x4x768) with
// COLUMN-PAIR convs (even/odd cols share the same 3-dword LDS window; parity
// via padded weight pairs) -> conv LDS reads halved. s_cv packed band-pairs
// (ll,lh) / (hl,hh) -> combine reads 2 dwords/pixel. Base conv + combine use
// the SAME (pair,rowblock) thread mapping so bacc[2][14] stays in registers.
// ---------------------------------------------------------------------------
__global__ __launch_bounds__(256, 5) void final_fused_v8(
    const float* __restrict__ x,
    const float* __restrict__ bw,
    const float* __restrict__ bb,
    const float* __restrict__ bs,
    const float* __restrict__ wt0,
    const float* __restrict__ wsc0,
    const float* __restrict__ c1,   // (B*C,4,56,56)
    const float* __restrict__ c2,   // (B*C,4,28,28)
    float* __restrict__ out)
{
    const int bc = blockIdx.z, c = bc % CC;
    const int t = threadIdx.x;

    __shared__ unsigned s_x[64 * 34];   // fp16 x-tile; phase>=3: s_cv01/s_cv23 overlay
    __shared__ unsigned s_sb[4 * 544];  // fp16 L0 subbands (32 rows x 17 dw)
    __shared__ float s_rec1[28 * 29];
    __shared__ float s_rec2[14 * 15];
    __shared__ unsigned s_w2[150];      // [5 knl][2 par][5 row][3] h2
    unsigned* const s_cv01 = s_x;       // [28][29] h2 (band0=lo, band1=hi)
    unsigned* const s_cv23 = s_x + 812; // [28][29] h2 (band2=lo, band3=hi)

    // ---- weights: folded, parity-padded half2 triplets ----
    if (t < 50) {
        int par = t & 1, row = (t >> 1) % 5, knl = t / 10;  // 0=base, 1..4=subband
        float wv[5];
        if (knl == 0) {
            float sc = bs[c];
            #pragma unroll
            for (int j = 0; j < 5; ++j) wv[j] = bw[c * 25 + row * 5 + j] * sc;
        } else {
            int s = knl - 1;
            float sc = 0.5f * wsc0[c * 4 + s];
            #pragma unroll
            for (int j = 0; j < 5; ++j) wv[j] = wt0[(c * 4 + s) * 25 + row * 5 + j] * sc;
        }
        unsigned* dst = &s_w2[((knl * 2 + par) * 5 + row) * 3];
        if (par == 0) {
            dst[0] = pkrtz(wv[0], wv[1]);
            dst[1] = pkrtz(wv[2], wv[3]);
            dst[2] = pkrtz(wv[4], 0.f);
        } else {
            dst[0] = pkrtz(0.f, wv[0]);
            dst[1] = pkrtz(wv[1], wv[2]);
            dst[2] = pkrtz(wv[3], wv[4]);
        }
    }

    // ---- coeff prefetch ----
    float c2v[4], c1v[4];
    const int p1 = t / 14, q1 = t % 14;
    if (t < 49) {
        const int p2 = t / 7, q2 = t % 7;
        const size_t b2 = (((size_t)bc * 4) * 28 + 7 * blockIdx.y + p2) * 28
                        + 7 * blockIdx.x + q2;
        #pragma unroll
        for (int s = 0; s < 4; ++s) c2v[s] = c2[b2 + (size_t)s * 784];
    }
    if (t < 196) {
        const size_t b1 = (((size_t)bc * 4) * 56 + 14 * blockIdx.y + p1) * 56
                        + 14 * blockIdx.x + q1;
        #pragma unroll
        for (int s = 0; s < 4; ++s) c1v[s] = c1[b1 + (size_t)s * 3136];
    }

    // ---- phase 1: stage 64x64 x-tile as packed fp16 ----
    const float* xp = x + (size_t)bc * HH * WW;
    const int gy0 = 56 * blockIdx.y - 4, gx0 = 56 * blockIdx.x - 4;
    for (int idx = t; idx < 1024; idx += 256) {
        int r = idx >> 4, j = idx & 15;
        int gr = gy0 + r, gc = gx0 + 4 * j;
        float4 v = make_float4(0.f, 0.f, 0.f, 0.f);
        if (gr >= 0 && gr < HH && gc >= 0 && gc + 3 < WW)
            v = *(const float4*)(xp + (size_t)gr * WW + gc);
        uint2 pp;
        pp.x = pkrtz(v.x, v.y);
        pp.y = pkrtz(v.z, v.w);
        *(uint2*)&s_x[r * 34 + 2 * j] = pp;
    }

    // ---- ihaar level 2: c2 -> s_rec2 (14x14) ----
    if (t < 49) {
        const int p2 = t / 7, q2 = t % 7;
        float ll = c2v[0], lh = c2v[1], hl = c2v[2], hh = c2v[3];
        float a  = 0.5f * (ll + lh + hl + hh);
        float b  = 0.5f * (ll - lh + hl - hh);
        float cv = 0.5f * (ll + lh - hl - hh);
        float d  = 0.5f * (ll - lh - hl + hh);
        float* rp = &s_rec2[(2 * p2) * 15 + 2 * q2];
        rp[0] = a; rp[1] = b; rp[15] = cv; rp[16] = d;
    }
    __syncthreads();

    // ---- phase 2a: butterfly (unscaled) -> s_sb ----
    for (int idx = t; idx < 512; idx += 256) {
        int sr = idx >> 4, g = idx & 15;
        uint2 tp = *(const uint2*)&s_x[(2 * sr) * 34 + 2 * g];
        uint2 bt = *(const uint2*)&s_x[(2 * sr + 1) * 34 + 2 * g];
        h2 t0 = u2h(tp.x), t1 = u2h(tp.y), b0 = u2h(bt.x), b1 = u2h(bt.y);
        float a0 = t0.x, e0 = t0.y, cc0 = b0.x, f0 = b0.y;
        float a1 = t1.x, e1 = t1.y, cc1 = b1.x, f1 = b1.y;
        float P0 = a0 + e0, M0 = a0 - e0, R0 = cc0 + f0, Q0 = cc0 - f0;
        float P1 = a1 + e1, M1 = a1 - e1, R1 = cc1 + f1, Q1 = cc1 - f1;
        s_sb[0 * 544 + sr * 17 + g] = pkrtz(P0 + R0, P1 + R1);
        s_sb[1 * 544 + sr * 17 + g] = pkrtz(M0 + Q0, M1 + Q1);
        s_sb[2 * 544 + sr * 17 + g] = pkrtz(P0 - R0, P1 - R1);
        s_sb[3 * 544 + sr * 17 + g] = pkrtz(M0 - Q0, M1 - Q1);
    }

    // ---- phase 2b: base conv, column pairs (2k,2k+1), rows rb*14..+13 ----
    const int kp = t % 28, rbp = t / 28;   // mapping shared with combine (t<112)
    float bacc_e[14], bacc_o[14];
    if (t < 112) {
        h2 we[5][3], wo[5][3];
        {
            const unsigned* wpe = &s_w2[0];
            const unsigned* wpo = &s_w2[15];
            #pragma unroll
            for (int ki = 0; ki < 5; ++ki)
                #pragma unroll
                for (int m = 0; m < 3; ++m) {
                    we[ki][m] = u2h(wpe[ki * 3 + m]);
                    wo[ki][m] = u2h(wpo[ki * 3 + m]);
                }
        }
        #pragma unroll
        for (int r = 0; r < 14; ++r) { bacc_e[r] = 0.f; bacc_o[r] = 0.f; }
        const int d0 = kp + 1;
        #pragma unroll
        for (int ri = 0; ri < 18; ++ri) {
            const unsigned* rp = &s_x[(rbp * 14 + ri + 2) * 34 + d0];
            h2 g0 = u2h(rp[0]), g1 = u2h(rp[1]), g2 = u2h(rp[2]);
            #pragma unroll
            for (int ki = 0; ki < 5; ++ki) {
                int r = ri - ki;
                if (r >= 0 && r < 14) {
                    bacc_e[r] = FDOT2(g0, we[ki][0],
                                FDOT2(g1, we[ki][1],
                                FDOT2(g2, we[ki][2], bacc_e[r])));
                    bacc_o[r] = FDOT2(g0, wo[ki][0],
                                FDOT2(g1, wo[ki][1],
                                FDOT2(g2, wo[ki][2], bacc_o[r])));
                }
            }
        }
    }

    // ---- phase 2c: ihaar level 1 -> s_rec1 (28x28) ----
    if (t < 196) {
        float ll = c1v[0] + s_rec2[p1 * 15 + q1];
        float lh = c1v[1], hl = c1v[2], hh = c1v[3];
        float a  = 0.5f * (ll + lh + hl + hh);
        float b  = 0.5f * (ll - lh + hl - hh);
        float cv = 0.5f * (ll + lh - hl - hh);
        float d  = 0.5f * (ll - lh - hl + hh);
        float* rp = &s_rec1[(2 * p1) * 29 + 2 * q1];
        rp[0] = a; rp[1] = b; rp[29] = cv; rp[30] = d;
    }
    __syncthreads();

    // ---- phase 3: subband convs, col pairs, 7-tall; packed s_cv writes ----
    if (t < 224) {
        const int s = t / 56, rem = t % 56;
        const int k = rem % 14, rb = rem / 14;      // subband col pair (2k,2k+1), rows rb*7..+6
        h2 we[5][3], wo[5][3];
        {
            const unsigned* wpe = &s_w2[((1 + s) * 2 + 0) * 15];
            const unsigned* wpo = &s_w2[((1 + s) * 2 + 1) * 15];
            #pragma unroll
            for (int ki = 0; ki < 5; ++ki)
                #pragma unroll
                for (int m = 0; m < 3; ++m) {
                    we[ki][m] = u2h(wpe[ki * 3 + m]);
                    wo[ki][m] = u2h(wpo[ki * 3 + m]);
                }
        }
        float acc_e[7], acc_o[7];
        #pragma unroll
        for (int r = 0; r < 7; ++r) { acc_e[r] = 0.f; acc_o[r] = 0.f; }
        #pragma unroll
        for (int ri = 0; ri < 11; ++ri) {
            const unsigned* rp = &s_sb[s * 544 + (rb * 7 + ri) * 17 + k];
            h2 g0 = u2h(rp[0]), g1 = u2h(rp[1]), g2 = u2h(rp[2]);
            #pragma unroll
            for (int ki = 0; ki < 5; ++ki) {
                int r = ri - ki;
                if (r >= 0 && r < 7) {
                    acc_e[r] = FDOT2(g0, we[ki][0],
                               FDOT2(g1, we[ki][1],
                               FDOT2(g2, we[ki][2], acc_e[r])));
                    acc_o[r] = FDOT2(g0, wo[ki][0],
                               FDOT2(g1, wo[ki][1],
                               FDOT2(g2, wo[ki][2], acc_o[r])));
                }
            }
        }
        // write as _Float16 halves into packed arrays (band0/1 -> cv01, 2/3 -> cv23)
        _Float16* base16 = reinterpret_cast<_Float16*>((s < 2) ? s_cv01 : s_cv23);
        const int hf = s & 1;
        #pragma unroll
        for (int r = 0; r < 7; ++r) {
            int p = rb * 7 + r;
            base16[(p * 29 + 2 * k) * 2 + hf]     = (_Float16)acc_e[r];
            base16[(p * 29 + 2 * k + 1) * 2 + hf] = (_Float16)acc_o[r];
        }
    }
    __syncthreads();

    // ---- phase 4: ihaar level 0 (2x2 blocks) + base + float2 stores ----
    if (t < 112) {
        const float bbv = bb[c];
        float* op = out + ((size_t)bc * HH + 56 * blockIdx.y + rbp * 14) * WW
                        + 56 * blockIdx.x + 2 * kp;
        #pragma unroll
        for (int j = 0; j < 7; ++j) {
            const int p = rbp * 7 + j;
            h2 v01 = u2h(s_cv01[p * 29 + kp]);
            h2 v23 = u2h(s_cv23[p * 29 + kp]);
            float ll = (float)v01.x + s_rec1[p * 29 + kp];
            float lh = (float)v01.y;
            float hl = (float)v23.x;
            float hh = (float)v23.y;
            float a  = 0.5f * (ll + lh + hl + hh) + bacc_e[2 * j]     + bbv;
            float b  = 0.5f * (ll - lh + hl - hh) + bacc_o[2 * j]     + bbv;
            float cv = 0.5f * (ll + lh - hl - hh) + bacc_e[2 * j + 1] + bbv;
            float d  = 0.5f * (ll - lh - hl + hh) + bacc_o[2 * j + 1] + bbv;
            *reinterpret_cast<float2*>(op + (size_t)(2 * j) * WW)     = make_float2(a, b);
            *reinterpret_cast<float2*>(op + (size_t)(2 * j + 1) * WW) = make_float2(cv, d);
        }
    }
}

extern "C" void kernel_launch(void* const* d_in, const int* in_sizes, int n_in,
                              void* d_out, int out_size, void* d_ws, size_t ws_size,
                              hipStream_t stream) {
    const float* x          = (const float*)d_in[0];
    const float* base_w     = (const float*)d_in[1];
    const float* base_b     = (const float*)d_in[2];
    const float* base_scale = (const float*)d_in[3];
    const float* wconv_w    = (const float*)d_in[4]; // (3, 384, 25)
    const float* wscale     = (const float*)d_in[5]; // (3, 384)
    float* out = (float*)d_out;
    float* ws  = (float*)d_ws;

    const size_t n1 = (size_t)BB * CC * 4 * 56 * 56;   // coeffs1

    float* coeffs1 = ws;
    float* coeffs2 = coeffs1 + n1;

    const int z = BB * CC;

    // levels 1+2 fully fused, one block per (b,c)
    levels_fused<<<z, 512, 0, stream>>>(
        x, coeffs1, coeffs2,
        wconv_w + 1 * 384 * 25, wscale + 1 * 384,
        wconv_w + 2 * 384 * 25, wscale + 2 * 384);
    // final: column-pair convs, packed s_cv, float2 stores
    final_fused_v8<<<dim3(4, 4, z), 256, 0, stream>>>(
        x, base_w, base_b, base_scale,
        wconv_w + 0 * 384 * 25, wscale + 0 * 384, coeffs1, coeffs2, out);
}

// Round 13
// 148.089 us; speedup vs baseline: 1.5173x; 1.0162x over previous
//
#include <hip/hip_runtime.h>

#define BB 8
#define CC 96
#define HH 224
#define WW 224

typedef _Float16 h2 __attribute__((ext_vector_type(2)));
__device__ __forceinline__ h2 u2h(unsigned u) { return __builtin_bit_cast(h2, u); }
__device__ __forceinline__ unsigned pkrtz(float a, float b) {
    return __builtin_bit_cast(unsigned, __builtin_amdgcn_cvt_pkrtz(a, b));
}

#if __has_builtin(__builtin_amdgcn_fdot2)
#define FDOT2(a, b, c) __builtin_amdgcn_fdot2((a), (b), (c), false)
#else
#define FDOT2(a, b, c) ((float)(a).x * (float)(b).x + (float)(a).y * (float)(b).y + (c))
#endif

// ---------------------------------------------------------------------------
// levels_fused: ONE block per (b,c). Levels 1+2 entirely in LDS. (unchanged)
// ---------------------------------------------------------------------------
__global__ __launch_bounds__(512, 4) void levels_fused(
    const float* __restrict__ x,
    float* __restrict__ c1,        // (B*C,4,56,56)
    float* __restrict__ c2,        // (B*C,4,28,28)
    const float* __restrict__ wt1, const float* __restrict__ ws1,
    const float* __restrict__ wt2, const float* __restrict__ ws2)
{
    const int bc = blockIdx.x, c = bc % CC;
    const int t = threadIdx.x;

    __shared__ unsigned s_c1[112 * 58];
    __shared__ unsigned s_sb1[4 * 60 * 31];
    __shared__ unsigned s_cur2[56 * 30];
    __shared__ unsigned s_sb2[4 * 32 * 17];
    __shared__ unsigned s_w2[240];

    for (int i = t; i < 4 * 60 * 31; i += 512) s_sb1[i] = 0;
    for (int i = t; i < 4 * 32 * 17; i += 512) s_sb2[i] = 0;

    if (t < 80) {
        int knl = t / 10;
        int par = t & 1, row = (t % 10) >> 1;
        int lvl = knl >> 2, s = knl & 3;
        const float* wt  = lvl ? wt2 : wt1;
        const float* wsc = lvl ? ws2 : ws1;
        float sc = 0.5f * wsc[c * 4 + s];
        float wv[5];
        #pragma unroll
        for (int j = 0; j < 5; ++j) wv[j] = wt[(c * 4 + s) * 25 + row * 5 + j] * sc;
        unsigned* dst = &s_w2[(knl * 2 + par) * 15 + row * 3];
        if (par == 0) {
            dst[0] = pkrtz(wv[0], wv[1]);
            dst[1] = pkrtz(wv[2], wv[3]);
            dst[2] = pkrtz(wv[4], 0.f);
        } else {
            dst[0] = pkrtz(0.f, wv[0]);
            dst[1] = pkrtz(wv[1], wv[2]);
            dst[2] = pkrtz(wv[3], wv[4]);
        }
    }

    const float* xp = x + (size_t)bc * HH * WW;
    for (int idx = t; idx < 112 * 56; idx += 512) {
        int r = idx / 56, g = idx % 56;
        const float* r0 = xp + (size_t)(2 * r) * WW + 4 * g;
        const float* r1 = r0 + WW;
        float4 a = *(const float4*)r0;
        float4 b = *(const float4*)r1;
        s_c1[r * 58 + g] = pkrtz(0.5f * (a.x + a.y + b.x + b.y),
                                 0.5f * (a.z + a.w + b.z + b.w));
    }
    __syncthreads();

    for (int idx = t; idx < 56 * 28; idx += 512) {
        int sr = idx / 28, sc2 = idx % 28;
        uint2 tp = *(const uint2*)&s_c1[(2 * sr) * 58 + 2 * sc2];
        uint2 bt = *(const uint2*)&s_c1[(2 * sr + 1) * 58 + 2 * sc2];
        h2 t0 = u2h(tp.x), t1 = u2h(tp.y), b0 = u2h(bt.x), b1 = u2h(bt.y);
        float P0 = (float)t0.x + (float)t0.y, M0 = (float)t0.x - (float)t0.y;
        float R0 = (float)b0.x + (float)b0.y, Q0 = (float)b0.x - (float)b0.y;
        float P1 = (float)t1.x + (float)t1.y, M1 = (float)t1.x - (float)t1.y;
        float R1 = (float)b1.x + (float)b1.y, Q1 = (float)b1.x - (float)b1.y;
        int o = (sr + 2) * 31 + (sc2 + 1);
        s_sb1[0 * 1860 + o] = pkrtz(P0 + R0, P1 + R1);
        s_sb1[1 * 1860 + o] = pkrtz(M0 + Q0, M1 + Q1);
        s_sb1[2 * 1860 + o] = pkrtz(P0 - R0, P1 - R1);
        s_sb1[3 * 1860 + o] = pkrtz(M0 - Q0, M1 - Q1);
        s_cur2[sr * 30 + sc2] = pkrtz(0.5f * (P0 + R0), 0.5f * (P1 + R1));
    }
    __syncthreads();

    if (t < 28 * 14) {
        int sr = t / 14, sc2 = t % 14;
        uint2 tp = *(const uint2*)&s_cur2[(2 * sr) * 30 + 2 * sc2];
        uint2 bt = *(const uint2*)&s_cur2[(2 * sr + 1) * 30 + 2 * sc2];
        h2 t0 = u2h(tp.x), t1 = u2h(tp.y), b0 = u2h(bt.x), b1 = u2h(bt.y);
        float P0 = (float)t0.x + (float)t0.y, M0 = (float)t0.x - (float)t0.y;
        float R0 = (float)b0.x + (float)b0.y, Q0 = (float)b0.x - (float)b0.y;
        float P1 = (float)t1.x + (float)t1.y, M1 = (float)t1.x - (float)t1.y;
        float R1 = (float)b1.x + (float)b1.y, Q1 = (float)b1.x - (float)b1.y;
        int o = (sr + 2) * 17 + (sc2 + 1);
        s_sb2[0 * 544 + o] = pkrtz(P0 + R0, P1 + R1);
        s_sb2[1 * 544 + o] = pkrtz(M0 + Q0, M1 + Q1);
        s_sb2[2 * 544 + o] = pkrtz(P0 - R0, P1 - R1);
        s_sb2[3 * 544 + o] = pkrtz(M0 - Q0, M1 - Q1);
    }

    {
        const int s = t >> 7, lane = t & 127;
        const int q = lane & 63, half = lane >> 6;
        if (q < 56) {
            const int par = q & 1, d0 = q >> 1, ps = half * 28;
            h2 w[5][3];
            {
                const unsigned* wp = &s_w2[(s * 2 + par) * 15];
                #pragma unroll
                for (int ki = 0; ki < 5; ++ki)
                    #pragma unroll
                    for (int m = 0; m < 3; ++m) w[ki][m] = u2h(wp[ki * 3 + m]);
            }
            float acc[28];
            #pragma unroll
            for (int r = 0; r < 28; ++r) acc[r] = 0.f;
            #pragma unroll
            for (int ri = 0; ri < 32; ++ri) {
                const unsigned* rp = &s_sb1[s * 1860 + (ps + ri) * 31 + d0];
                h2 g0 = u2h(rp[0]), g1 = u2h(rp[1]), g2 = u2h(rp[2]);
                #pragma unroll
                for (int ki = 0; ki < 5; ++ki) {
                    int r = ri - ki;
                    if (r >= 0 && r < 28)
                        acc[r] = FDOT2(g0, w[ki][0],
                                 FDOT2(g1, w[ki][1],
                                 FDOT2(g2, w[ki][2], acc[r])));
                }
            }
            const size_t ob = ((size_t)(bc * 4 + s) * 56 + ps) * 56 + q;
            #pragma unroll
            for (int r = 0; r < 28; ++r)
                c1[ob + (size_t)r * 56] = acc[r];
        }
    }
    __syncthreads();

    if (t < 112) {
        const int s = t / 28, q = t % 28;
        const int par = q & 1, d0 = q >> 1;
        h2 w[5][3];
        {
            const unsigned* wp = &s_w2[((4 + s) * 2 + par) * 15];
            #pragma unroll
            for (int ki = 0; ki < 5; ++ki)
                #pragma unroll
                for (int m = 0; m < 3; ++m) w[ki][m] = u2h(wp[ki * 3 + m]);
        }
        float acc[28];
        #pragma unroll
        for (int r = 0; r < 28; ++r) acc[r] = 0.f;
        #pragma unroll
        for (int ri = 0; ri < 32; ++ri) {
            const unsigned* rp = &s_sb2[s * 544 + ri * 17 + d0];
            h2 g0 = u2h(rp[0]), g1 = u2h(rp[1]), g2 = u2h(rp[2]);
            #pragma unroll
            for (int ki = 0; ki < 5; ++ki) {
                int r = ri - ki;
                if (r >= 0 && r < 28)
                    acc[r] = FDOT2(g0, w[ki][0],
                             FDOT2(g1, w[ki][1],
                             FDOT2(g2, w[ki][2], acc[r])));
            }
        }
        const size_t ob = (size_t)(bc * 4 + s) * 28 * 28 + q;
        #pragma unroll
        for (int r = 0; r < 28; ++r)
            c2[ob + (size_t)r * 28] = acc[r];
    }
}

// ---------------------------------------------------------------------------
// final_fused_v9: column-pair convs with FULL thread utilization.
//   base conv : 196 thr = 28 pairs x 7 row-blocks (8 rows) -> bacc_e/o[8]
//   subband   : 224 thr = 4 bands x 14 pairs x 4 row-blocks (7 rows)
//   combine   : 196 thr, same (pair,rb) as base -> bacc stays in registers
// Packed s_cv band-pairs; float2 stores. 256 thr, 56x56 tile, grid 4x4x768.
// ---------------------------------------------------------------------------
__global__ __launch_bounds__(256, 5) void final_fused_v9(
    const float* __restrict__ x,
    const float* __restrict__ bw,
    const float* __restrict__ bb,
    const float* __restrict__ bs,
    const float* __restrict__ wt0,
    const float* __restrict__ wsc0,
    const float* __restrict__ c1,   // (B*C,4,56,56)
    const float* __restrict__ c2,   // (B*C,4,28,28)
    float* __restrict__ out)
{
    const int bc = blockIdx.z, c = bc % CC;
    const int t = threadIdx.x;

    __shared__ unsigned s_x[64 * 34];   // fp16 x-tile; phase>=3: s_cv overlay
    __shared__ unsigned s_sb[4 * 544];  // fp16 L0 subbands (32 rows x 17 dw)
    __shared__ float s_rec1[28 * 29];
    __shared__ float s_rec2[14 * 15];
    __shared__ unsigned s_w2[150];      // [5 knl][2 par][5 row][3] h2
    unsigned* const s_cv01 = s_x;       // [28][29] h2 (band0, band1)
    unsigned* const s_cv23 = s_x + 812; // [28][29] h2 (band2, band3)

    // ---- weights: folded, parity-padded half2 triplets ----
    if (t < 50) {
        int par = t & 1, row = (t >> 1) % 5, knl = t / 10;  // 0=base, 1..4=subband
        float wv[5];
        if (knl == 0) {
            float sc = bs[c];
            #pragma unroll
            for (int j = 0; j < 5; ++j) wv[j] = bw[c * 25 + row * 5 + j] * sc;
        } else {
            int s = knl - 1;
            float sc = 0.5f * wsc0[c * 4 + s];
            #pragma unroll
            for (int j = 0; j < 5; ++j) wv[j] = wt0[(c * 4 + s) * 25 + row * 5 + j] * sc;
        }
        unsigned* dst = &s_w2[((knl * 2 + par) * 5 + row) * 3];
        if (par == 0) {
            dst[0] = pkrtz(wv[0], wv[1]);
            dst[1] = pkrtz(wv[2], wv[3]);
            dst[2] = pkrtz(wv[4], 0.f);
        } else {
            dst[0] = pkrtz(0.f, wv[0]);
            dst[1] = pkrtz(wv[1], wv[2]);
            dst[2] = pkrtz(wv[3], wv[4]);
        }
    }

    // ---- coeff prefetch ----
    float c2v[4], c1v[4];
    const int p1 = t / 14, q1 = t % 14;
    if (t < 49) {
        const int p2 = t / 7, q2 = t % 7;
        const size_t b2 = (((size_t)bc * 4) * 28 + 7 * blockIdx.y + p2) * 28
                        + 7 * blockIdx.x + q2;
        #pragma unroll
        for (int s = 0; s < 4; ++s) c2v[s] = c2[b2 + (size_t)s * 784];
    }
    if (t < 196) {
        const size_t b1 = (((size_t)bc * 4) * 56 + 14 * blockIdx.y + p1) * 56
                        + 14 * blockIdx.x + q1;
        #pragma unroll
        for (int s = 0; s < 4; ++s) c1v[s] = c1[b1 + (size_t)s * 3136];
    }

    // ---- phase 1: stage 64x64 x-tile as packed fp16 ----
    const float* xp = x + (size_t)bc * HH * WW;
    const int gy0 = 56 * blockIdx.y - 4, gx0 = 56 * blockIdx.x - 4;
    for (int idx = t; idx < 1024; idx += 256) {
        int r = idx >> 4, j = idx & 15;
        int gr = gy0 + r, gc = gx0 + 4 * j;
        float4 v = make_float4(0.f, 0.f, 0.f, 0.f);
        if (gr >= 0 && gr < HH && gc >= 0 && gc + 3 < WW)
            v = *(const float4*)(xp + (size_t)gr * WW + gc);
        uint2 pp;
        pp.x = pkrtz(v.x, v.y);
        pp.y = pkrtz(v.z, v.w);
        *(uint2*)&s_x[r * 34 + 2 * j] = pp;
    }

    // ---- ihaar level 2: c2 -> s_rec2 (14x14) ----
    if (t < 49) {
        const int p2 = t / 7, q2 = t % 7;
        float ll = c2v[0], lh = c2v[1], hl = c2v[2], hh = c2v[3];
        float a  = 0.5f * (ll + lh + hl + hh);
        float b  = 0.5f * (ll - lh + hl - hh);
        float cv = 0.5f * (ll + lh - hl - hh);
        float d  = 0.5f * (ll - lh - hl + hh);
        float* rp = &s_rec2[(2 * p2) * 15 + 2 * q2];
        rp[0] = a; rp[1] = b; rp[15] = cv; rp[16] = d;
    }
    __syncthreads();

    // ---- phase 2a: butterfly (unscaled) -> s_sb ----
    for (int idx = t; idx < 512; idx += 256) {
        int sr = idx >> 4, g = idx & 15;
        uint2 tp = *(const uint2*)&s_x[(2 * sr) * 34 + 2 * g];
        uint2 bt = *(const uint2*)&s_x[(2 * sr + 1) * 34 + 2 * g];
        h2 t0 = u2h(tp.x), t1 = u2h(tp.y), b0 = u2h(bt.x), b1 = u2h(bt.y);
        float a0 = t0.x, e0 = t0.y, cc0 = b0.x, f0 = b0.y;
        float a1 = t1.x, e1 = t1.y, cc1 = b1.x, f1 = b1.y;
        float P0 = a0 + e0, M0 = a0 - e0, R0 = cc0 + f0, Q0 = cc0 - f0;
        float P1 = a1 + e1, M1 = a1 - e1, R1 = cc1 + f1, Q1 = cc1 - f1;
        s_sb[0 * 544 + sr * 17 + g] = pkrtz(P0 + R0, P1 + R1);
        s_sb[1 * 544 + sr * 17 + g] = pkrtz(M0 + Q0, M1 + Q1);
        s_sb[2 * 544 + sr * 17 + g] = pkrtz(P0 - R0, P1 - R1);
        s_sb[3 * 544 + sr * 17 + g] = pkrtz(M0 - Q0, M1 - Q1);
    }

    // ---- phase 2b: base conv, col pairs (2kp,2kp+1), 8-row blocks ----
    const int kp = t % 28, rbp = t / 28;   // rbp 0..6 for t<196; shared with combine
    float bacc_e[8], bacc_o[8];
    if (t < 196) {
        h2 we[5][3], wo[5][3];
        {
            const unsigned* wpe = &s_w2[0];
            const unsigned* wpo = &s_w2[15];
            #pragma unroll
            for (int ki = 0; ki < 5; ++ki)
                #pragma unroll
                for (int m = 0; m < 3; ++m) {
                    we[ki][m] = u2h(wpe[ki * 3 + m]);
                    wo[ki][m] = u2h(wpo[ki * 3 + m]);
                }
        }
        #pragma unroll
        for (int r = 0; r < 8; ++r) { bacc_e[r] = 0.f; bacc_o[r] = 0.f; }
        const int d0 = kp + 1;
        #pragma unroll
        for (int ri = 0; ri < 12; ++ri) {
            const unsigned* rp = &s_x[(rbp * 8 + ri + 2) * 34 + d0];
            h2 g0 = u2h(rp[0]), g1 = u2h(rp[1]), g2 = u2h(rp[2]);
            #pragma unroll
            for (int ki = 0; ki < 5; ++ki) {
                int r = ri - ki;
                if (r >= 0 && r < 8) {
                    bacc_e[r] = FDOT2(g0, we[ki][0],
                                FDOT2(g1, we[ki][1],
                                FDOT2(g2, we[ki][2], bacc_e[r])));
                    bacc_o[r] = FDOT2(g0, wo[ki][0],
                                FDOT2(g1, wo[ki][1],
                                FDOT2(g2, wo[ki][2], bacc_o[r])));
                }
            }
        }
    }

    // ---- phase 2c: ihaar level 1 -> s_rec1 (28x28) ----
    if (t < 196) {
        float ll = c1v[0] + s_rec2[p1 * 15 + q1];
        float lh = c1v[1], hl = c1v[2], hh = c1v[3];
        float a  = 0.5f * (ll + lh + hl + hh);
        float b  = 0.5f * (ll - lh + hl - hh);
        float cv = 0.5f * (ll + lh - hl - hh);
        float d  = 0.5f * (ll - lh - hl + hh);
        float* rp = &s_rec1[(2 * p1) * 29 + 2 * q1];
        rp[0] = a; rp[1] = b; rp[29] = cv; rp[30] = d;
    }
    __syncthreads();

    // ---- phase 3: subband convs, col pairs, 7-row blocks; packed writes ----
    if (t < 224) {
        const int s = t / 56, rem = t % 56;
        const int k = rem % 14, rb = rem / 14;   // pair (2k,2k+1), rows rb*7..+6
        h2 we[5][3], wo[5][3];
        {
            const unsigned* wpe = &s_w2[((1 + s) * 2 + 0) * 15];
            const unsigned* wpo = &s_w2[((1 + s) * 2 + 1) * 15];
            #pragma unroll
            for (int ki = 0; ki < 5; ++ki)
                #pragma unroll
                for (int m = 0; m < 3; ++m) {
                    we[ki][m] = u2h(wpe[ki * 3 + m]);
                    wo[ki][m] = u2h(wpo[ki * 3 + m]);
                }
        }
        float acc_e[7], acc_o[7];
        #pragma unroll
        for (int r = 0; r < 7; ++r) { acc_e[r] = 0.f; acc_o[r] = 0.f; }
        #pragma unroll
        for (int ri = 0; ri < 11; ++ri) {
            const unsigned* rp = &s_sb[s * 544 + (rb * 7 + ri) * 17 + k];
            h2 g0 = u2h(rp[0]), g1 = u2h(rp[1]), g2 = u2h(rp[2]);
            #pragma unroll
            for (int ki = 0; ki < 5; ++ki) {
                int r = ri - ki;
                if (r >= 0 && r < 7) {
                    acc_e[r] = FDOT2(g0, we[ki][0],
                               FDOT2(g1, we[ki][1],
                               FDOT2(g2, we[ki][2], acc_e[r])));
                    acc_o[r] = FDOT2(g0, wo[ki][0],
                               FDOT2(g1, wo[ki][1],
                               FDOT2(g2, wo[ki][2], acc_o[r])));
                }
            }
        }
        _Float16* base16 = reinterpret_cast<_Float16*>((s < 2) ? s_cv01 : s_cv23);
        const int hf = s & 1;
        #pragma unroll
        for (int r = 0; r < 7; ++r) {
            int p = rb * 7 + r;
            base16[(p * 29 + 2 * k) * 2 + hf]     = (_Float16)acc_e[r];
            base16[(p * 29 + 2 * k + 1) * 2 + hf] = (_Float16)acc_o[r];
        }
    }
    __syncthreads();

    // ---- phase 4: ihaar level 0 + base + float2 stores (same map as 2b) ----
    if (t < 196) {
        const float bbv = bb[c];
        float* op = out + ((size_t)bc * HH + 56 * blockIdx.y + rbp * 8) * WW
                        + 56 * blockIdx.x + 2 * kp;
        #pragma unroll
        for (int j = 0; j < 4; ++j) {
            const int p = rbp * 4 + j;
            h2 v01 = u2h(s_cv01[p * 29 + kp]);
            h2 v23 = u2h(s_cv23[p * 29 + kp]);
            float ll = (float)v01.x + s_rec1[p * 29 + kp];
            float lh = (float)v01.y;
            float hl = (float)v23.x;
            float hh = (float)v23.y;
            float a  = 0.5f * (ll + lh + hl + hh) + bacc_e[2 * j]     + bbv;
            float b  = 0.5f * (ll - lh + hl - hh) + bacc_o[2 * j]     + bbv;
            float cv = 0.5f * (ll + lh - hl - hh) + bacc_e[2 * j + 1] + bbv;
            float d  = 0.5f * (ll - lh - hl + hh) + bacc_o[2 * j + 1] + bbv;
            *reinterpret_cast<float2*>(op + (size_t)(2 * j) * WW)     = make_float2(a, b);
            *reinterpret_cast<float2*>(op + (size_t)(2 * j + 1) * WW) = make_float2(cv, d);
        }
    }
}

extern "C" void kernel_launch(void* const* d_in, const int* in_sizes, int n_in,
                              void* d_out, int out_size, void* d_ws, size_t ws_size,
                              hipStream_t stream) {
    const float* x          = (const float*)d_in[0];
    const float* base_w     = (const float*)d_in[1];
    const float* base_b     = (const float*)d_in[2];
    const float* base_scale = (const float*)d_in[3];
    const float* wconv_w    = (const float*)d_in[4]; // (3, 384, 25)
    const float* wscale     = (const float*)d_in[5]; // (3, 384)
    float* out = (float*)d_out;
    float* ws  = (float*)d_ws;

    const size_t n1 = (size_t)BB * CC * 4 * 56 * 56;   // coeffs1

    float* coeffs1 = ws;
    float* coeffs2 = coeffs1 + n1;

    const int z = BB * CC;

    // levels 1+2 fully fused, one block per (b,c)
    levels_fused<<<z, 512, 0, stream>>>(
        x, coeffs1, coeffs2,
        wconv_w + 1 * 384 * 25, wscale + 1 * 384,
        wconv_w + 2 * 384 * 25, wscale + 2 * 384);
    // final: column-pair convs, full-occupancy mappings
    final_fused_v9<<<dim3(4, 4, z), 256, 0, stream>>>(
        x, base_w, base_b, base_scale,
        wconv_w + 0 * 384 * 25, wscale + 0 * 384, coeffs1, coeffs2, out);
}

// Round 14
// 130.457 us; speedup vs baseline: 1.7223x; 1.1352x over previous
//
#include <hip/hip_runtime.h>

#define BB 8
#define CC 96
#define HH 224
#define WW 224

typedef _Float16 h2 __attribute__((ext_vector_type(2)));
__device__ __forceinline__ h2 u2h(unsigned u) { return __builtin_bit_cast(h2, u); }
__device__ __forceinline__ unsigned pkrtz(float a, float b) {
    return __builtin_bit_cast(unsigned, __builtin_amdgcn_cvt_pkrtz(a, b));
}

#if __has_builtin(__builtin_amdgcn_fdot2)
#define FDOT2(a, b, c) __builtin_amdgcn_fdot2((a), (b), (c), false)
#else
#define FDOT2(a, b, c) ((float)(a).x * (float)(b).x + (float)(a).y * (float)(b).y + (c))
#endif

// ---------------------------------------------------------------------------
// levels_fused2: ONE block per (b,c). Levels 1+2 AND full reconstruction
// (ihaar2 + ihaar1) in LDS. Only output: rec1 (112x112, packed fp16 h2).
// LDS overlays (all on dead regions, barrier-separated):
//   c1_01/c1_23 (conv results, h2 band-pairs) -> on s_c1
//   c2_01/c2_23                               -> on s_cur2
//   rec2 (56x56 fp32)                         -> on s_sb1
// ---------------------------------------------------------------------------
__global__ __launch_bounds__(512, 4) void levels_fused2(
    const float* __restrict__ x,
    unsigned* __restrict__ rec1g,  // (B*C, 112, 56) h2 dwords
    const float* __restrict__ wt1, const float* __restrict__ ws1,
    const float* __restrict__ wt2, const float* __restrict__ ws2)
{
    const int bc = blockIdx.x, c = bc % CC;
    const int t = threadIdx.x;

    __shared__ unsigned s_c1[112 * 58];      // cur1; later c1_01/c1_23 overlay
    __shared__ unsigned s_sb1[4 * 60 * 31];  // L1 subbands; later rec2 overlay
    __shared__ unsigned s_cur2[56 * 30];     // cur2; later c2_01/c2_23 overlay
    __shared__ unsigned s_sb2[4 * 32 * 17];  // L2 subbands
    __shared__ unsigned s_w2[240];

    unsigned* const c1_01 = s_c1;            // [56][57] h2 (band0,band1)
    unsigned* const c1_23 = s_c1 + 3192;     // [56][57] h2 (band2,band3)
    unsigned* const c2_01 = s_cur2;          // [28][29]
    unsigned* const c2_23 = s_cur2 + 812;    // [28][29]
    float*    const rec2  = reinterpret_cast<float*>(s_sb1);  // [56][57] fp32

    for (int i = t; i < 4 * 60 * 31; i += 512) s_sb1[i] = 0;
    for (int i = t; i < 4 * 32 * 17; i += 512) s_sb2[i] = 0;

    if (t < 80) {
        int knl = t / 10;
        int par = t & 1, row = (t % 10) >> 1;
        int lvl = knl >> 2, s = knl & 3;
        const float* wt  = lvl ? wt2 : wt1;
        const float* wsc = lvl ? ws2 : ws1;
        float sc = 0.5f * wsc[c * 4 + s];
        float wv[5];
        #pragma unroll
        for (int j = 0; j < 5; ++j) wv[j] = wt[(c * 4 + s) * 25 + row * 5 + j] * sc;
        unsigned* dst = &s_w2[(knl * 2 + par) * 15 + row * 3];
        if (par == 0) {
            dst[0] = pkrtz(wv[0], wv[1]);
            dst[1] = pkrtz(wv[2], wv[3]);
            dst[2] = pkrtz(wv[4], 0.f);
        } else {
            dst[0] = pkrtz(0.f, wv[0]);
            dst[1] = pkrtz(wv[1], wv[2]);
            dst[2] = pkrtz(wv[3], wv[4]);
        }
    }

    // ---- phase A: stage cur1 = level-0 LL from x ----
    const float* xp = x + (size_t)bc * HH * WW;
    for (int idx = t; idx < 112 * 56; idx += 512) {
        int r = idx / 56, g = idx % 56;
        const float* r0 = xp + (size_t)(2 * r) * WW + 4 * g;
        const float* r1 = r0 + WW;
        float4 a = *(const float4*)r0;
        float4 b = *(const float4*)r1;
        s_c1[r * 58 + g] = pkrtz(0.5f * (a.x + a.y + b.x + b.y),
                                 0.5f * (a.z + a.w + b.z + b.w));
    }
    __syncthreads();

    // ---- phase B: butterfly cur1 -> sb1 (+ cur2) ----
    for (int idx = t; idx < 56 * 28; idx += 512) {
        int sr = idx / 28, sc2 = idx % 28;
        uint2 tp = *(const uint2*)&s_c1[(2 * sr) * 58 + 2 * sc2];
        uint2 bt = *(const uint2*)&s_c1[(2 * sr + 1) * 58 + 2 * sc2];
        h2 t0 = u2h(tp.x), t1 = u2h(tp.y), b0 = u2h(bt.x), b1 = u2h(bt.y);
        float P0 = (float)t0.x + (float)t0.y, M0 = (float)t0.x - (float)t0.y;
        float R0 = (float)b0.x + (float)b0.y, Q0 = (float)b0.x - (float)b0.y;
        float P1 = (float)t1.x + (float)t1.y, M1 = (float)t1.x - (float)t1.y;
        float R1 = (float)b1.x + (float)b1.y, Q1 = (float)b1.x - (float)b1.y;
        int o = (sr + 2) * 31 + (sc2 + 1);
        s_sb1[0 * 1860 + o] = pkrtz(P0 + R0, P1 + R1);
        s_sb1[1 * 1860 + o] = pkrtz(M0 + Q0, M1 + Q1);
        s_sb1[2 * 1860 + o] = pkrtz(P0 - R0, P1 - R1);
        s_sb1[3 * 1860 + o] = pkrtz(M0 - Q0, M1 - Q1);
        s_cur2[sr * 30 + sc2] = pkrtz(0.5f * (P0 + R0), 0.5f * (P1 + R1));
    }
    __syncthreads();

    // ---- phase C1: butterfly cur2 -> sb2 ----
    if (t < 28 * 14) {
        int sr = t / 14, sc2 = t % 14;
        uint2 tp = *(const uint2*)&s_cur2[(2 * sr) * 30 + 2 * sc2];
        uint2 bt = *(const uint2*)&s_cur2[(2 * sr + 1) * 30 + 2 * sc2];
        h2 t0 = u2h(tp.x), t1 = u2h(tp.y), b0 = u2h(bt.x), b1 = u2h(bt.y);
        float P0 = (float)t0.x + (float)t0.y, M0 = (float)t0.x - (float)t0.y;
        float R0 = (float)b0.x + (float)b0.y, Q0 = (float)b0.x - (float)b0.y;
        float P1 = (float)t1.x + (float)t1.y, M1 = (float)t1.x - (float)t1.y;
        float R1 = (float)b1.x + (float)b1.y, Q1 = (float)b1.x - (float)b1.y;
        int o = (sr + 2) * 17 + (sc2 + 1);
        s_sb2[0 * 544 + o] = pkrtz(P0 + R0, P1 + R1);
        s_sb2[1 * 544 + o] = pkrtz(M0 + Q0, M1 + Q1);
        s_sb2[2 * 544 + o] = pkrtz(P0 - R0, P1 - R1);
        s_sb2[3 * 544 + o] = pkrtz(M0 - Q0, M1 - Q1);
    }

    // ---- phase C2: L1 conv -> c1_01/c1_23 (LDS overlay on dead s_c1) ----
    {
        const int s = t >> 7, lane = t & 127;
        const int q = lane & 63, half = lane >> 6;
        if (q < 56) {
            const int par = q & 1, d0 = q >> 1, ps = half * 28;
            h2 w[5][3];
            {
                const unsigned* wp = &s_w2[(s * 2 + par) * 15];
                #pragma unroll
                for (int ki = 0; ki < 5; ++ki)
                    #pragma unroll
                    for (int m = 0; m < 3; ++m) w[ki][m] = u2h(wp[ki * 3 + m]);
            }
            float acc[28];
            #pragma unroll
            for (int r = 0; r < 28; ++r) acc[r] = 0.f;
            #pragma unroll
            for (int ri = 0; ri < 32; ++ri) {
                const unsigned* rp = &s_sb1[s * 1860 + (ps + ri) * 31 + d0];
                h2 g0 = u2h(rp[0]), g1 = u2h(rp[1]), g2 = u2h(rp[2]);
                #pragma unroll
                for (int ki = 0; ki < 5; ++ki) {
                    int r = ri - ki;
                    if (r >= 0 && r < 28)
                        acc[r] = FDOT2(g0, w[ki][0],
                                 FDOT2(g1, w[ki][1],
                                 FDOT2(g2, w[ki][2], acc[r])));
                }
            }
            _Float16* dstH = reinterpret_cast<_Float16*>((s < 2) ? c1_01 : c1_23);
            const int hf = s & 1;
            #pragma unroll
            for (int r = 0; r < 28; ++r)
                dstH[((ps + r) * 57 + q) * 2 + hf] = (_Float16)acc[r];
        }
    }
    __syncthreads();

    // ---- phase D: L2 conv -> c2_01/c2_23 (overlay on dead s_cur2) ----
    if (t < 112) {
        const int s = t / 28, q = t % 28;
        const int par = q & 1, d0 = q >> 1;
        h2 w[5][3];
        {
            const unsigned* wp = &s_w2[((4 + s) * 2 + par) * 15];
            #pragma unroll
            for (int ki = 0; ki < 5; ++ki)
                #pragma unroll
                for (int m = 0; m < 3; ++m) w[ki][m] = u2h(wp[ki * 3 + m]);
        }
        float acc[28];
        #pragma unroll
        for (int r = 0; r < 28; ++r) acc[r] = 0.f;
        #pragma unroll
        for (int ri = 0; ri < 32; ++ri) {
            const unsigned* rp = &s_sb2[s * 544 + ri * 17 + d0];
            h2 g0 = u2h(rp[0]), g1 = u2h(rp[1]), g2 = u2h(rp[2]);
            #pragma unroll
            for (int ki = 0; ki < 5; ++ki) {
                int r = ri - ki;
                if (r >= 0 && r < 28)
                    acc[r] = FDOT2(g0, w[ki][0],
                             FDOT2(g1, w[ki][1],
                             FDOT2(g2, w[ki][2], acc[r])));
            }
        }
        _Float16* dstH = reinterpret_cast<_Float16*>((s < 2) ? c2_01 : c2_23);
        const int hf = s & 1;
        #pragma unroll
        for (int r = 0; r < 28; ++r)
            dstH[(r * 29 + q) * 2 + hf] = (_Float16)acc[r];
    }
    __syncthreads();

    // ---- phase E: ihaar2 (next_ll=0): c2 -> rec2 fp32 (overlay on s_sb1) ----
    for (int i = t; i < 784; i += 512) {
        int p2 = i / 28, q2 = i % 28;
        h2 v01 = u2h(c2_01[p2 * 29 + q2]);
        h2 v23 = u2h(c2_23[p2 * 29 + q2]);
        float ll = v01.x, lh = v01.y, hl = v23.x, hh = v23.y;
        float a  = 0.5f * (ll + lh + hl + hh);
        float b  = 0.5f * (ll - lh + hl - hh);
        float cv = 0.5f * (ll + lh - hl - hh);
        float d  = 0.5f * (ll - lh - hl + hh);
        float* rp = &rec2[(2 * p2) * 57 + 2 * q2];
        rp[0] = a; rp[1] = b; rp[57] = cv; rp[58] = d;
    }
    __syncthreads();

    // ---- phase F: ihaar1: (c1, LL += rec2) -> rec1 global (packed h2) ----
    unsigned* rg = rec1g + (size_t)bc * 112 * 56;
    for (int i = t; i < 3136; i += 512) {
        int p1 = i / 56, q1 = i % 56;
        h2 v01 = u2h(c1_01[p1 * 57 + q1]);
        h2 v23 = u2h(c1_23[p1 * 57 + q1]);
        float ll = (float)v01.x + rec2[p1 * 57 + q1];
        float lh = v01.y, hl = v23.x, hh = v23.y;
        float a  = 0.5f * (ll + lh + hl + hh);
        float b  = 0.5f * (ll - lh + hl - hh);
        float cv = 0.5f * (ll + lh - hl - hh);
        float d  = 0.5f * (ll - lh - hl + hh);
        rg[(size_t)(2 * p1) * 56 + q1]     = pkrtz(a, cv) ;
        rg[(size_t)(2 * p1 + 1) * 56 + q1] = 0;  // placeholder overwritten below
        // NOTE: row 2p1 holds cols (2q1, 2q1+1) = (a, b); row 2p1+1 = (cv, d)
        rg[(size_t)(2 * p1) * 56 + q1]     = pkrtz(a, b);
        rg[(size_t)(2 * p1 + 1) * 56 + q1] = pkrtz(cv, d);
    }
}

// ---------------------------------------------------------------------------
// final_fused_v10: v5 core (fp16 LDS + fdot2, 256 thr, 56x56 tile) with the
// reconstruction phases REMOVED — rec1 arrives precomputed (packed fp16).
// ---------------------------------------------------------------------------
__global__ __launch_bounds__(256, 7) void final_fused_v10(
    const float* __restrict__ x,
    const float* __restrict__ bw,
    const float* __restrict__ bb,
    const float* __restrict__ bs,
    const float* __restrict__ wt0,
    const float* __restrict__ wsc0,
    const unsigned* __restrict__ rec1g,  // (B*C,112,56) h2
    float* __restrict__ out)
{
    const int bc = blockIdx.z, c = bc % CC;
    const int t = threadIdx.x;

    __shared__ unsigned s_x2[64 * 34];   // h2 x-tile; phase>=3: fp16 s_cv overlay
    __shared__ unsigned s_sb[4 * 544];   // h2 subbands, stride 17
    __shared__ float s_rec1[28 * 29];
    __shared__ unsigned s_w2[150];
    _Float16* const s_cvh = reinterpret_cast<_Float16*>(s_x2);

    if (t < 50) {
        int par = t & 1, row = (t >> 1) % 5, knl = t / 10;
        float wv[5];
        if (knl == 0) {
            float sc = bs[c];
            #pragma unroll
            for (int j = 0; j < 5; ++j) wv[j] = bw[c * 25 + row * 5 + j] * sc;
        } else {
            int s = knl - 1;
            float sc = 0.5f * wsc0[c * 4 + s];
            #pragma unroll
            for (int j = 0; j < 5; ++j) wv[j] = wt0[(c * 4 + s) * 25 + row * 5 + j] * sc;
        }
        unsigned* dst = &s_w2[((knl * 2 + par) * 5 + row) * 3];
        if (par == 0) {
            dst[0] = pkrtz(wv[0], wv[1]);
            dst[1] = pkrtz(wv[2], wv[3]);
            dst[2] = pkrtz(wv[4], 0.f);
        } else {
            dst[0] = pkrtz(0.f, wv[0]);
            dst[1] = pkrtz(wv[1], wv[2]);
            dst[2] = pkrtz(wv[3], wv[4]);
        }
    }

    // ---- rec1 tile load (392 dwords; 2 per thread for t<196) ----
    if (t < 196) {
        #pragma unroll
        for (int k = 0; k < 2; ++k) {
            int idx = 2 * t + k;
            int r = idx / 14, d = idx % 14;
            unsigned v = rec1g[((size_t)bc * 112 + 28 * blockIdx.y + r) * 56
                               + 14 * blockIdx.x + d];
            h2 hv = u2h(v);
            s_rec1[r * 29 + 2 * d]     = hv.x;
            s_rec1[r * 29 + 2 * d + 1] = hv.y;
        }
    }

    // ---- phase 1: stage 64x64 x-tile as packed fp16 ----
    const float* xp = x + (size_t)bc * HH * WW;
    const int gy0 = 56 * blockIdx.y - 4, gx0 = 56 * blockIdx.x - 4;
    for (int idx = t; idx < 1024; idx += 256) {
        int r = idx >> 4, j = idx & 15;
        int gr = gy0 + r, gc = gx0 + 4 * j;
        float4 v = make_float4(0.f, 0.f, 0.f, 0.f);
        if (gr >= 0 && gr < HH && gc >= 0 && gc + 3 < WW)
            v = *(const float4*)(xp + (size_t)gr * WW + gc);
        uint2 pp;
        pp.x = pkrtz(v.x, v.y);
        pp.y = pkrtz(v.z, v.w);
        *(uint2*)&s_x2[r * 34 + 2 * j] = pp;
    }
    __syncthreads();

    // ---- phase 2a: haar butterfly (unscaled) ----
    for (int idx = t; idx < 512; idx += 256) {
        int sr = idx >> 4, g = idx & 15;
        uint2 tp = *(const uint2*)&s_x2[(2 * sr) * 34 + 2 * g];
        uint2 bt = *(const uint2*)&s_x2[(2 * sr + 1) * 34 + 2 * g];
        h2 t0 = u2h(tp.x), t1 = u2h(tp.y), b0 = u2h(bt.x), b1 = u2h(bt.y);
        float a0 = t0.x, e0 = t0.y, cc0 = b0.x, f0 = b0.y;
        float a1 = t1.x, e1 = t1.y, cc1 = b1.x, f1 = b1.y;
        float P0 = a0 + e0, M0 = a0 - e0, R0 = cc0 + f0, Q0 = cc0 - f0;
        float P1 = a1 + e1, M1 = a1 - e1, R1 = cc1 + f1, Q1 = cc1 - f1;
        s_sb[0 * 544 + sr * 17 + g] = pkrtz(P0 + R0, P1 + R1);
        s_sb[1 * 544 + sr * 17 + g] = pkrtz(M0 + Q0, M1 + Q1);
        s_sb[2 * 544 + sr * 17 + g] = pkrtz(P0 - R0, P1 - R1);
        s_sb[3 * 544 + sr * 17 + g] = pkrtz(M0 - Q0, M1 - Q1);
    }

    // ---- phase 2b: base conv via fdot2 (bacc in regs) ----
    const int q4 = t % 56, rb4 = t / 56;
    float bacc[14];
    if (t < 224) {
        const int par = q4 & 1, d0 = (q4 + 2) >> 1;
        h2 w[5][3];
        {
            const unsigned* wp = &s_w2[(par * 5) * 3];
            #pragma unroll
            for (int ki = 0; ki < 5; ++ki)
                #pragma unroll
                for (int m = 0; m < 3; ++m) w[ki][m] = u2h(wp[ki * 3 + m]);
        }
        #pragma unroll
        for (int r = 0; r < 14; ++r) bacc[r] = 0.f;
        #pragma unroll
        for (int ri = 0; ri < 18; ++ri) {
            const unsigned* rp = &s_x2[(rb4 * 14 + ri + 2) * 34 + d0];
            h2 g0 = u2h(rp[0]), g1 = u2h(rp[1]), g2 = u2h(rp[2]);
            #pragma unroll
            for (int ki = 0; ki < 5; ++ki) {
                int r = ri - ki;
                if (r >= 0 && r < 14)
                    bacc[r] = FDOT2(g0, w[ki][0],
                              FDOT2(g1, w[ki][1],
                              FDOT2(g2, w[ki][2], bacc[r])));
            }
        }
    }
    __syncthreads();

    // ---- phase 3: subband convs via fdot2 -> fp16 s_cv (overlay on s_x2) ----
    {
        const int s = t >> 6, u = t & 63;
        if (u < 56) {
            const int q = u % 28, rb = u / 28;
            const int par = q & 1, d0 = q >> 1;
            h2 w[5][3];
            {
                const unsigned* wp = &s_w2[(((1 + s) * 2 + par) * 5) * 3];
                #pragma unroll
                for (int ki = 0; ki < 5; ++ki)
                    #pragma unroll
                    for (int m = 0; m < 3; ++m) w[ki][m] = u2h(wp[ki * 3 + m]);
            }
            float acc[14];
            #pragma unroll
            for (int r = 0; r < 14; ++r) acc[r] = 0.f;
            #pragma unroll
            for (int ri = 0; ri < 18; ++ri) {
                const unsigned* rp = &s_sb[s * 544 + (rb * 14 + ri) * 17 + d0];
                h2 g0 = u2h(rp[0]), g1 = u2h(rp[1]), g2 = u2h(rp[2]);
                #pragma unroll
                for (int ki = 0; ki < 5; ++ki) {
                    int r = ri - ki;
                    if (r >= 0 && r < 14)
                        acc[r] = FDOT2(g0, w[ki][0],
                                 FDOT2(g1, w[ki][1],
                                 FDOT2(g2, w[ki][2], acc[r])));
                }
            }
            #pragma unroll
            for (int r = 0; r < 14; ++r)
                s_cvh[(s * 28 + rb * 14 + r) * 29 + q] = (_Float16)acc[r];
        }
    }
    __syncthreads();

    // ---- phase 4: ihaar level 0 + combine with base + store ----
    if (t < 224) {
        const float bbv = bb[c];
        const int qs = q4 >> 1;
        const float sx = (q4 & 1) ? -1.f : 1.f;
        float* op = out + ((size_t)bc * HH + 56 * blockIdx.y + rb4 * 14) * WW
                        + 56 * blockIdx.x + q4;
        #pragma unroll
        for (int j = 0; j < 7; ++j) {
            const int p = rb4 * 7 + j;
            float ll = (float)s_cvh[(0 * 28 + p) * 29 + qs] + s_rec1[p * 29 + qs];
            float lh = (float)s_cvh[(1 * 28 + p) * 29 + qs];
            float hl = (float)s_cvh[(2 * 28 + p) * 29 + qs];
            float hh = (float)s_cvh[(3 * 28 + p) * 29 + qs];
            float e0 = ll + sx * lh;
            float e1 = hl + sx * hh;
            float top = 0.5f * (e0 + e1);
            float bot = 0.5f * (e0 - e1);
            op[(size_t)(2 * j) * WW]     = bacc[2 * j]     + bbv + top;
            op[(size_t)(2 * j + 1) * WW] = bacc[2 * j + 1] + bbv + bot;
        }
    }
}

extern "C" void kernel_launch(void* const* d_in, const int* in_sizes, int n_in,
                              void* d_out, int out_size, void* d_ws, size_t ws_size,
                              hipStream_t stream) {
    const float* x          = (const float*)d_in[0];
    const float* base_w     = (const float*)d_in[1];
    const float* base_b     = (const float*)d_in[2];
    const float* base_scale = (const float*)d_in[3];
    const float* wconv_w    = (const float*)d_in[4]; // (3, 384, 25)
    const float* wscale     = (const float*)d_in[5]; // (3, 384)
    float* out = (float*)d_out;
    unsigned* rec1 = (unsigned*)d_ws;   // (B*C,112,56) h2 dwords

    const int z = BB * CC;

    // levels 1+2 + full reconstruction; writes rec1 only
    levels_fused2<<<z, 512, 0, stream>>>(
        x, rec1,
        wconv_w + 1 * 384 * 25, wscale + 1 * 384,
        wconv_w + 2 * 384 * 25, wscale + 2 * 384);
    // final: base conv + L0 haar+conv + combine with rec1
    final_fused_v10<<<dim3(4, 4, z), 256, 0, stream>>>(
        x, base_w, base_b, base_scale,
        wconv_w + 0 * 384 * 25, wscale + 0 * 384, rec1, out);
}